// Round 2
// baseline (212.499 us; speedup 1.0000x reference)
//
#include <hip/hip_runtime.h>
#include <math.h>

#define N_NODES 50000
#define N_EDGES 800000
#define D_IN    64
#define H_HID   16
#define C_OUT   40
#define SCAN_B  512
#define N_SCAN_BLOCKS ((N_NODES + SCAN_B - 1) / SCAN_B)   // 98

// ---- pass 1 over edges: degree histograms (src for norm, dst for CSR) ----
__global__ void count_kernel(const int* __restrict__ src, const int* __restrict__ dst,
                             int* __restrict__ deg_src, int* __restrict__ deg_dst) {
    int e = blockIdx.x * blockDim.x + threadIdx.x;
    if (e < N_EDGES) {
        atomicAdd(&deg_src[src[e]], 1);
        atomicAdd(&deg_dst[dst[e]], 1);
    }
}

__global__ void dinv_kernel(const int* __restrict__ deg_src, float* __restrict__ dinv) {
    int i = blockIdx.x * blockDim.x + threadIdx.x;
    if (i < N_NODES) {
        int d = deg_src[i];
        dinv[i] = (d > 0) ? rsqrtf((float)d) : 0.0f;
    }
}

// ---- hierarchical exclusive scan of deg_dst -> rowptr ----
__global__ void scan1_kernel(const int* __restrict__ deg_dst, int* __restrict__ rowptr,
                             int* __restrict__ blocksum) {
    __shared__ int s[SCAN_B];
    int i = blockIdx.x * SCAN_B + threadIdx.x;
    int v = (i < N_NODES) ? deg_dst[i] : 0;
    s[threadIdx.x] = v;
    __syncthreads();
    for (int off = 1; off < SCAN_B; off <<= 1) {
        int t = (threadIdx.x >= off) ? s[threadIdx.x - off] : 0;
        __syncthreads();
        s[threadIdx.x] += t;
        __syncthreads();
    }
    if (i < N_NODES) rowptr[i] = s[threadIdx.x] - v;          // local exclusive
    if (threadIdx.x == SCAN_B - 1) blocksum[blockIdx.x] = s[threadIdx.x];
}

__global__ void scan2_kernel(int* __restrict__ blocksum) {
    if (threadIdx.x == 0 && blockIdx.x == 0) {
        int acc = 0;
        for (int i = 0; i < N_SCAN_BLOCKS; ++i) { int v = blocksum[i]; blocksum[i] = acc; acc += v; }
    }
}

__global__ void scan3_kernel(const int* __restrict__ blocksum, int* __restrict__ rowptr,
                             int* __restrict__ cursor) {
    int i = blockIdx.x * SCAN_B + threadIdx.x;
    if (i < N_NODES) {
        int v = rowptr[i] + blocksum[blockIdx.x];
        rowptr[i] = v;
        cursor[i] = v;
    }
    if (i == 0) rowptr[N_NODES] = N_EDGES;
}

// ---- pass 2 over edges: scatter src ids into dst-grouped CSR ----
__global__ void scatter_kernel(const int* __restrict__ src, const int* __restrict__ dst,
                               int* __restrict__ cursor, int* __restrict__ col) {
    int e = blockIdx.x * blockDim.x + threadIdx.x;
    if (e < N_EDGES) {
        int pos = atomicAdd(&cursor[dst[e]], 1);
        col[pos] = src[e];
    }
}

// ---- xw0 = x@W1[0]; sxw1 = dinv * (x@W1[1]) ----
__global__ void xw_kernel(const float* __restrict__ x, const float* __restrict__ W1,
                          const float* __restrict__ dinv,
                          float* __restrict__ xw0, float* __restrict__ sxw1) {
    __shared__ float sW[2 * D_IN * H_HID];   // 8 KB
    for (int i = threadIdx.x; i < 2 * D_IN * H_HID; i += blockDim.x)
        sW[i] = W1[i];
    __syncthreads();

    int t = blockIdx.x * blockDim.x + threadIdx.x;
    if (t >= N_NODES * H_HID) return;
    int node = t >> 4;
    int f    = t & 15;
    const float* xr = x + node * D_IN;
    float a0 = 0.f, a1 = 0.f;
    #pragma unroll
    for (int d = 0; d < D_IN; ++d) {
        float xv = xr[d];
        a0 += xv * sW[d * H_HID + f];
        a1 += xv * sW[D_IN * H_HID + d * H_HID + f];
    }
    xw0[t]  = a0;
    sxw1[t] = dinv[node] * a1;
}

// ---- layer-1 aggregation (gather) + epilogue: h = relu(xw0 - dinv*Σ sxw1[s] + b1) ----
__global__ void gather1_kernel(const int* __restrict__ rowptr, const int* __restrict__ col,
                               const float* __restrict__ dinv, const float* __restrict__ sxw1,
                               const float* __restrict__ xw0, const float* __restrict__ b1,
                               float* __restrict__ h, float* __restrict__ sh) {
    int t = blockIdx.x * blockDim.x + threadIdx.x;
    int node = t >> 4;
    int f    = t & 15;
    if (node >= N_NODES) return;
    int beg = rowptr[node], end = rowptr[node + 1];
    float acc = 0.f;
    for (int j = beg; j < end; ++j) {
        int s = col[j];                     // same addr across the 16-lane group: broadcast
        acc += sxw1[s * H_HID + f];         // 64B coalesced line per group
    }
    float di = dinv[node];
    float v = xw0[t] - di * acc + b1[f];
    v = fmaxf(v, 0.f);
    h[t]  = v;
    sh[t] = di * v;
}

// ---- layer-2 aggregation (gather): agg2 = -dinv * Σ sh[s] ----
__global__ void gather2_kernel(const int* __restrict__ rowptr, const int* __restrict__ col,
                               const float* __restrict__ dinv, const float* __restrict__ sh,
                               float* __restrict__ agg2) {
    int t = blockIdx.x * blockDim.x + threadIdx.x;
    int node = t >> 4;
    int f    = t & 15;
    if (node >= N_NODES) return;
    int beg = rowptr[node], end = rowptr[node + 1];
    float acc = 0.f;
    for (int j = beg; j < end; ++j) {
        int s = col[j];
        acc += sh[s * H_HID + f];
    }
    agg2[t] = -dinv[node] * acc;
}

// ---- final: out = log_softmax(h@W2[0] + agg2@W2[1] + b2) ----
__global__ void layer2_kernel(const float* __restrict__ h, const float* __restrict__ agg2,
                              const float* __restrict__ W2, const float* __restrict__ b2,
                              float* __restrict__ out) {
    __shared__ float sW0[H_HID * C_OUT];
    __shared__ float sW1[H_HID * C_OUT];
    __shared__ float sb[C_OUT];
    for (int i = threadIdx.x; i < H_HID * C_OUT; i += blockDim.x) {
        sW0[i] = W2[i];
        sW1[i] = W2[H_HID * C_OUT + i];
    }
    if (threadIdx.x < C_OUT) sb[threadIdx.x] = b2[threadIdx.x];
    __syncthreads();

    int node = blockIdx.x * blockDim.x + threadIdx.x;
    if (node >= N_NODES) return;
    float hv[H_HID], t1[H_HID];
    #pragma unroll
    for (int f = 0; f < H_HID; ++f) {
        hv[f] = h[node * H_HID + f];
        t1[f] = agg2[node * H_HID + f];
    }
    float o[C_OUT];
    float mx = -1e30f;
    #pragma unroll
    for (int c = 0; c < C_OUT; ++c) {
        float acc = sb[c];
        #pragma unroll
        for (int f = 0; f < H_HID; ++f) {
            acc += hv[f] * sW0[f * C_OUT + c];
            acc += t1[f] * sW1[f * C_OUT + c];
        }
        o[c] = acc;
        mx = fmaxf(mx, acc);
    }
    float sum = 0.f;
    #pragma unroll
    for (int c = 0; c < C_OUT; ++c) sum += expf(o[c] - mx);
    float lse = mx + logf(sum);
    #pragma unroll
    for (int c = 0; c < C_OUT; ++c) out[node * C_OUT + c] = o[c] - lse;
}

extern "C" void kernel_launch(void* const* d_in, const int* in_sizes, int n_in,
                              void* d_out, int out_size, void* d_ws, size_t ws_size,
                              hipStream_t stream) {
    const float* x   = (const float*)d_in[0];
    const int*   ei  = (const int*)d_in[1];
    const float* W1  = (const float*)d_in[2];
    const float* b1  = (const float*)d_in[3];
    const float* W2  = (const float*)d_in[4];
    const float* b2  = (const float*)d_in[5];
    float* out = (float*)d_out;

    const int* src = ei;            // edge_index[0]
    const int* dst = ei + N_EDGES;  // edge_index[1]

    // workspace layout (4-byte elements)
    char* wsb = (char*)d_ws;
    int*   deg_src  = (int*)wsb;                               // N
    int*   deg_dst  = deg_src + N_NODES;                       // N   (contiguous with deg_src for one memset)
    float* dinv     = (float*)(deg_dst + N_NODES);             // N
    int*   rowptr   = (int*)(dinv + N_NODES);                  // N+1
    int*   cursor   = rowptr + N_NODES + 1;                    // N
    int*   blocksum = cursor + N_NODES;                        // 128
    int*   col      = blocksum + 128;                          // E
    float* xw0      = (float*)(col + N_EDGES);                 // N*16
    float* sxw1     = xw0  + (size_t)N_NODES * H_HID;          // N*16
    float* h        = sxw1 + (size_t)N_NODES * H_HID;          // N*16
    float* sh       = h    + (size_t)N_NODES * H_HID;          // N*16
    float* agg2     = sh   + (size_t)N_NODES * H_HID;          // N*16

    hipMemsetAsync(deg_src, 0, (size_t)2 * N_NODES * sizeof(int), stream);

    const int B = 256;
    count_kernel<<<(N_EDGES + B - 1) / B, B, 0, stream>>>(src, dst, deg_src, deg_dst);
    dinv_kernel<<<(N_NODES + B - 1) / B, B, 0, stream>>>(deg_src, dinv);
    scan1_kernel<<<N_SCAN_BLOCKS, SCAN_B, 0, stream>>>(deg_dst, rowptr, blocksum);
    scan2_kernel<<<1, 64, 0, stream>>>(blocksum);
    scan3_kernel<<<N_SCAN_BLOCKS, SCAN_B, 0, stream>>>(blocksum, rowptr, cursor);
    scatter_kernel<<<(N_EDGES + B - 1) / B, B, 0, stream>>>(src, dst, cursor, col);

    xw_kernel<<<(N_NODES * H_HID + B - 1) / B, B, 0, stream>>>(x, W1, dinv, xw0, sxw1);
    gather1_kernel<<<(N_NODES * H_HID + B - 1) / B, B, 0, stream>>>(rowptr, col, dinv, sxw1, xw0, b1, h, sh);
    gather2_kernel<<<(N_NODES * H_HID + B - 1) / B, B, 0, stream>>>(rowptr, col, dinv, sh, agg2);
    layer2_kernel<<<(N_NODES + B - 1) / B, B, 0, stream>>>(h, agg2, W2, b2, out);
}